// Round 7
// baseline (676.606 us; speedup 1.0000x reference)
//
#include <hip/hip_runtime.h>
#include <stdint.h>

typedef short short8 __attribute__((ext_vector_type(8)));
typedef float f32x4 __attribute__((ext_vector_type(4)));

#define B_    4
#define M_    2048
#define D_    1024
#define NH_   16
#define DH_   64
#define LOG2E 1.44269504f

__device__ __forceinline__ short f2bf(float f) {
  union { float f; uint32_t u; } v; v.f = f;
  uint32_t r = (v.u + 0x7fffu + ((v.u >> 16) & 1u)) >> 16;  // RNE
  return (short)r;
}

__device__ __forceinline__ void gl_lds16(const void* g, void* l) {
  __builtin_amdgcn_global_load_lds(
      (__attribute__((address_space(1))) void*)(g),
      (__attribute__((address_space(3))) void*)(l),
      16, 0, 0);
}

__device__ __forceinline__ f32x4 mfma16(short8 a, short8 b, f32x4 c) {
  return __builtin_amdgcn_mfma_f32_16x16x32_bf16(a, b, c, 0, 0, 0);
}

// ---------------- fp32 -> bf16 cast, all 5 tensors in one launch ----------------
__global__ __launch_bounds__(256) void cvt_all(const float* __restrict__ H,
                                               const float* __restrict__ s0,
                                               const float* __restrict__ s1,
                                               const float* __restrict__ s2,
                                               const float* __restrict__ s3,
                                               short* __restrict__ dH,
                                               short* __restrict__ d0,
                                               short* __restrict__ d1,
                                               short* __restrict__ d2,
                                               short* __restrict__ d3) {
  const int bidx = blockIdx.x;
  const float* src;
  short* dst;
  int i;
  if (bidx < 8192) {
    src = H; dst = dH; i = bidx * 256 + threadIdx.x;
  } else {
    const int y = (bidx - 8192) >> 10;
    src = (y == 0) ? s0 : (y == 1) ? s1 : (y == 2) ? s2 : s3;
    dst = (y == 0) ? d0 : (y == 1) ? d1 : (y == 2) ? d2 : d3;
    i = ((bidx - 8192) & 1023) * 256 + threadIdx.x;
  }
  float4 v = ((const float4*)src)[i];
  short4 o;
  o.x = f2bf(v.x); o.y = f2bf(v.y); o.z = f2bf(v.z); o.w = f2bf(v.w);
  ((short4*)dst)[i] = o;
}

// ---------------- fused QKV projection GEMM ----------------
// Q/K: operand-SWAPPED mfma computes C^T in-register -> each lane holds 4
// consecutive n-values -> direct packed short4 global stores (no LDS epi).
// V: normal operand order -> lane holds 4 consecutive tokens -> direct
// short4 stores into V^T (B,NH,DH,M). LDS 16 KB; 4 blocks/CU target.
__global__ __launch_bounds__(256, 4) void gemm_qkv(const short* __restrict__ A,
                                                   const short* __restrict__ Wqb,
                                                   const short* __restrict__ Wkb,
                                                   const short* __restrict__ Wvb,
                                                   const float* __restrict__ bq,
                                                   const float* __restrict__ bk,
                                                   const float* __restrict__ bv,
                                                   short* __restrict__ Qo,
                                                   short* __restrict__ Ko,
                                                   short* __restrict__ Vo) {
  __shared__ char smem_raw[16384];
  short* Abuf = (short*)smem_raw;          // 128x32 (8 KB)
  short* Bbuf = (short*)smem_raw + 4096;   // 128x32 (8 KB)

  const int L = blockIdx.x + 8 * (blockIdx.y + 64 * blockIdx.z);
  const int xcd = L & 7;
  const int s = L >> 3;
  const int m_local = s & 7;
  const int nz = s >> 3;
  const int nt = nz & 7, z = nz >> 3;
  const int m0 = (xcd * 8 + m_local) * 128;
  const int n0 = nt * 128;

  const short* Bt = (z == 0) ? Wqb : (z == 1) ? Wkb : Wvb;
  const float* bias = (z == 0) ? bq : (z == 1) ? bk : bv;
  const float scale = (z == 0) ? 0.125f : 1.0f;

  const int tid = threadIdx.x;
  const int w = tid >> 6, l = tid & 63;
  const int q4 = l >> 4, c = l & 15;
  const int wr = w >> 1, wc = w & 1;

  f32x4 acc[4][4] = {};
  const int arow = (l >> 2);
  const int acol = (l & 3) * 8;

  for (int kk = 0; kk < 32; ++kk) {
    const int k0 = kk * 32;
#pragma unroll
    for (int st = 0; st < 2; ++st) {
      const int chunk = w * 2 + st;
      gl_lds16(A + (size_t)(m0 + chunk * 16 + arow) * 1024 + k0 + acol,
               Abuf + chunk * 512);
      gl_lds16(Bt + (size_t)(n0 + chunk * 16 + arow) * 1024 + k0 + acol,
               Bbuf + chunk * 512);
    }
    __syncthreads();
    short8 af[4], bfr[4];
#pragma unroll
    for (int i = 0; i < 4; ++i)
      af[i] = *(const short8*)(Abuf + (wr * 64 + i * 16 + c) * 32 + q4 * 8);
#pragma unroll
    for (int j = 0; j < 4; ++j)
      bfr[j] = *(const short8*)(Bbuf + (wc * 64 + j * 16 + c) * 32 + q4 * 8);
    if (z < 2) {  // block-uniform: C^T orientation (rows<->n, cols<->token)
#pragma unroll
      for (int i = 0; i < 4; ++i)
#pragma unroll
        for (int j = 0; j < 4; ++j)
          acc[i][j] = mfma16(bfr[j], af[i], acc[i][j]);
    } else {      // C orientation (rows<->token, cols<->d)
#pragma unroll
      for (int i = 0; i < 4; ++i)
#pragma unroll
        for (int j = 0; j < 4; ++j)
          acc[i][j] = mfma16(af[i], bfr[j], acc[i][j]);
    }
    __syncthreads();
  }

  if (z < 2) {
    // C^T frags: token = m0+wr*64+i*16+c ; n = n0+wc*64+j*16+q4*4+r (r packed)
    short* out = (z == 0) ? Qo : Ko;
#pragma unroll
    for (int i = 0; i < 4; ++i) {
      const size_t t = (size_t)(m0 + wr * 64 + i * 16 + c);
#pragma unroll
      for (int j = 0; j < 4; ++j) {
        const int nb = n0 + wc * 64 + j * 16 + q4 * 4;
        const float4 b4 = *(const float4*)(bias + nb);
        short4 pk;
        pk.x = f2bf((acc[i][j][0] + b4.x) * scale);
        pk.y = f2bf((acc[i][j][1] + b4.y) * scale);
        pk.z = f2bf((acc[i][j][2] + b4.z) * scale);
        pk.w = f2bf((acc[i][j][3] + b4.w) * scale);
        *(short4*)(out + t * 1024 + nb) = pk;
      }
    }
  } else {
    // C frags: d-col = n0+wc*64+j*16+c ; token = m0+wr*64+i*16+q4*4+r (r packed)
    const int bb = m0 >> 11;
    const int tokb = m0 & 2047;
#pragma unroll
    for (int j = 0; j < 4; ++j) {
      const int colg = n0 + wc * 64 + j * 16 + c;
      const float bvv = bias[colg];
      const int hh = colg >> 6, dd = colg & 63;
      short* vp = Vo + ((size_t)(bb * NH_ + hh) * DH_ + dd) * M_;
#pragma unroll
      for (int i = 0; i < 4; ++i) {
        short4 pk;
        pk.x = f2bf(acc[i][j][0] + bvv);
        pk.y = f2bf(acc[i][j][1] + bvv);
        pk.z = f2bf(acc[i][j][2] + bvv);
        pk.w = f2bf(acc[i][j][3] + bvv);
        *(short4*)(vp + tokb + wr * 64 + i * 16 + q4 * 4) = pk;
      }
    }
  }
}

// ---------------- output projection GEMM: swapped mfma, direct float4 stores ----------------
__global__ __launch_bounds__(256, 4) void gemm_oproj(const short* __restrict__ A,
                                                     const short* __restrict__ Bt,
                                                     const float* __restrict__ bias,
                                                     const int* __restrict__ pmask,
                                                     float* __restrict__ outp) {
  __shared__ char smem[12288];
  short* Abuf = (short*)smem;            // 128x32 (8 KB)
  short* Bbuf = (short*)(smem + 8192);   // 64x32  (4 KB)

  const int L = blockIdx.x + 16 * blockIdx.y;  // 1024 blocks
  const int xcd = L & 7;
  const int s = L >> 3;
  const int m_local = s & 7;
  const int nt = s >> 3;
  const int m0 = (xcd * 8 + m_local) * 128;
  const int n0 = nt * 64;

  const int tid = threadIdx.x;
  const int w = tid >> 6, l = tid & 63;
  const int q4 = l >> 4, c = l & 15;
  const int wr = w >> 1, wc = w & 1;

  f32x4 acc[4][2] = {};
  const int arow = (l >> 2);
  const int acol = (l & 3) * 8;

  for (int kk = 0; kk < 32; ++kk) {
    const int k0 = kk * 32;
#pragma unroll
    for (int st = 0; st < 2; ++st) {
      const int chunk = w * 2 + st;
      gl_lds16(A + (size_t)(m0 + chunk * 16 + arow) * 1024 + k0 + acol,
               Abuf + chunk * 512);
    }
    gl_lds16(Bt + (size_t)(n0 + w * 16 + arow) * 1024 + k0 + acol,
             Bbuf + w * 512);
    __syncthreads();
    short8 af[4], bfr[2];
#pragma unroll
    for (int i = 0; i < 4; ++i)
      af[i] = *(const short8*)(Abuf + (wr * 64 + i * 16 + c) * 32 + q4 * 8);
#pragma unroll
    for (int j = 0; j < 2; ++j)
      bfr[j] = *(const short8*)(Bbuf + (wc * 32 + j * 16 + c) * 32 + q4 * 8);
#pragma unroll
    for (int i = 0; i < 4; ++i)
#pragma unroll
      for (int j = 0; j < 2; ++j)
        acc[i][j] = mfma16(bfr[j], af[i], acc[i][j]);  // C^T orientation
    __syncthreads();
  }

  // C^T frags: token = m0+wr*64+i*16+c ; n = n0+wc*32+j*16+q4*4+r (r packed)
#pragma unroll
  for (int i = 0; i < 4; ++i) {
    const int t = m0 + wr * 64 + i * 16 + c;
    const float mmv = (pmask[t] > 0) ? 1.0f : 0.0f;
#pragma unroll
    for (int j = 0; j < 2; ++j) {
      const int nb = n0 + wc * 32 + j * 16 + q4 * 4;
      const float4 b4 = *(const float4*)(bias + nb);
      float4 v;
      v.x = (acc[i][j][0] + b4.x) * mmv;
      v.y = (acc[i][j][1] + b4.y) * mmv;
      v.z = (acc[i][j][2] + b4.z) * mmv;
      v.w = (acc[i][j][3] + b4.w) * mmv;
      *(float4*)(outp + (size_t)t * 1024 + nb) = v;
    }
  }
}

// ---------------- windowed attention (unchanged from R6) ----------------
__global__ __launch_bounds__(256) void attn_kernel(const short* __restrict__ Qb,
                                                   const short* __restrict__ Kb,
                                                   const short* __restrict__ Vtb,
                                                   const int* __restrict__ pmask,
                                                   short* __restrict__ Attb) {
  __shared__ char smem[20480];
  short* Ks0 = (short*)smem;             // 32x64 (4 KB)
  short* Ks1 = (short*)(smem + 4096);
  short* Vs0 = (short*)(smem + 8192);    // 64x32 (4 KB)
  short* Vs1 = (short*)(smem + 12288);
  short* Ps  = (short*)(smem + 16384);   // 4 waves x 16x32 (4 KB)

  const int tid = threadIdx.x;
  const int w = tid >> 6, l = tid & 63;
  const int q4 = l >> 4, c = l & 15;
  const int qt = blockIdx.x, h = blockIdx.y, b = blockIdx.z;
  const short* Qrow = Qb + (size_t)(b * M_) * D_ + h * DH_;
  const short* Kbase = Kb + (size_t)(b * M_) * D_ + h * DH_;
  const short* Vbase = Vtb + (size_t)(b * NH_ + h) * DH_ * M_;
  const int qrow0 = qt * 64 + w * 16;

  short8 aq0 = *(const short8*)(Qrow + (size_t)(qrow0 + c) * D_ + q4 * 8);
  short8 aq1 = *(const short8*)(Qrow + (size_t)(qrow0 + c) * D_ + 32 + q4 * 8);

  const int jt0 = max(0, 2 * qt - 2);
  const int jt1 = min(M_ / 32 - 1, 2 * qt + 3);

  const int kh = tid >> 7, krow = (tid >> 2) & 31, ch = tid & 3;
  const int vrow = tid >> 2;

  {
    const int j0 = jt0 * 32;
    gl_lds16(Kbase + (size_t)(j0 + krow) * D_ + kh * 32 + ch * 8, (char*)Ks0 + tid * 16);
    gl_lds16(Vbase + (size_t)vrow * M_ + j0 + ch * 8, (char*)Vs0 + tid * 16);
  }
  __syncthreads();

  f32x4 o[4] = {};
  float lrun[4] = {0.f, 0.f, 0.f, 0.f};
  short* Pw = Ps + w * 512;

  for (int jt = jt0; jt <= jt1; ++jt) {
    const int buf = (jt - jt0) & 1;
    const int j0 = jt * 32;
    if (jt < jt1) {
      const int j0n = j0 + 32;
      gl_lds16(Kbase + (size_t)(j0n + krow) * D_ + kh * 32 + ch * 8,
               (char*)(buf ? Ks0 : Ks1) + tid * 16);
      gl_lds16(Vbase + (size_t)vrow * M_ + j0n + ch * 8,
               (char*)(buf ? Vs0 : Vs1) + tid * 16);
    }
    const short* Kt = buf ? Ks1 : Ks0;
    const short* Vt = buf ? Vs1 : Vs0;
    short8 b00 = *(const short8*)(Kt + c * 32 + q4 * 8);
    short8 b10 = *(const short8*)(Kt + 1024 + c * 32 + q4 * 8);
    short8 b01 = *(const short8*)(Kt + (16 + c) * 32 + q4 * 8);
    short8 b11 = *(const short8*)(Kt + 1024 + (16 + c) * 32 + q4 * 8);
    f32x4 s0 = {}, s1 = {};
    s0 = mfma16(aq0, b00, s0);
    s0 = mfma16(aq1, b10, s0);
    s1 = mfma16(aq0, b01, s1);
    s1 = mfma16(aq1, b11, s1);

    const float w0m = (pmask[b * M_ + j0 + c] > 0) ? 1.f : 0.f;
    const float w1m = (pmask[b * M_ + j0 + 16 + c] > 0) ? 1.f : 0.f;

#pragma unroll
    for (int r = 0; r < 4; ++r) {
      const int qr = qrow0 + q4 * 4 + r;
      const float d0 = fminf(fabsf((float)(qr - (j0 + c))), 28.0f);
      const float d1 = fminf(fabsf((float)(qr - (j0 + 16 + c))), 28.0f);
      const float p0 = exp2f((s0[r] - d0) * LOG2E) * w0m;
      const float p1 = exp2f((s1[r] - d1) * LOG2E) * w1m;
      Pw[(q4 * 4 + r) * 32 + c] = f2bf(p0);
      Pw[(q4 * 4 + r) * 32 + 16 + c] = f2bf(p1);
      lrun[r] += p0 + p1;
    }
    short8 pa = *(const short8*)(Pw + c * 32 + q4 * 8);
#pragma unroll
    for (int f = 0; f < 4; ++f) {
      short8 bv = *(const short8*)(Vt + (f * 16 + c) * 32 + q4 * 8);
      o[f] = mfma16(pa, bv, o[f]);
    }
    __syncthreads();
  }

#pragma unroll
  for (int r = 0; r < 4; ++r) {
#pragma unroll
    for (int off = 1; off < 16; off <<= 1)
      lrun[r] += __shfl_xor(lrun[r], off);
  }

  short* Cb = (short*)smem;
#pragma unroll
  for (int r = 0; r < 4; ++r) {
    const float inv = 1.0f / lrun[r];
#pragma unroll
    for (int f = 0; f < 4; ++f)
      Cb[(w * 16 + q4 * 4 + r) * 72 + f * 16 + c] = f2bf(o[f][r] * inv);
  }
  __syncthreads();
#pragma unroll
  for (int p = 0; p < 2; ++p) {
    const int u = p * 256 + tid;
    const int row = u >> 3, seg = u & 7;
    *(short8*)(Attb + (size_t)(b * M_ + qt * 64 + row) * D_ + h * DH_ + seg * 8) =
        *(const short8*)(Cb + row * 72 + seg * 8);
  }
}

extern "C" void kernel_launch(void* const* d_in, const int* in_sizes, int n_in,
                              void* d_out, int out_size, void* d_ws, size_t ws_size,
                              hipStream_t stream) {
  const float* H     = (const float*)d_in[0];
  const int*   pmask = (const int*)d_in[1];
  const float* Wq    = (const float*)d_in[2];
  const float* bq    = (const float*)d_in[3];
  const float* Wk    = (const float*)d_in[4];
  const float* bk    = (const float*)d_in[5];
  const float* Wv    = (const float*)d_in[6];
  const float* bv    = (const float*)d_in[7];
  const float* Wo    = (const float*)d_in[8];
  const float* bo    = (const float*)d_in[9];
  float* out = (float*)d_out;
  char* ws = (char*)d_ws;

  short* Hb   = (short*)(ws);                  // 16 MB  (B*M x D bf16)
  short* Attb = (short*)(ws);                  // alias of Hb (dead after qkv)
  short* Wqb  = (short*)(ws + (16u << 20));
  short* Wkb  = (short*)(ws + (18u << 20));
  short* Wvb  = (short*)(ws + (20u << 20));
  short* Wob  = (short*)(ws + (22u << 20));
  short* Qb   = (short*)(ws + (24u << 20));    // 16 MB (B*M,1024), pre-scaled 1/8
  short* Kb2  = (short*)(ws + (40u << 20));    // 16 MB (B*M,1024)
  short* Vtb  = (short*)(ws + (56u << 20));    // 16 MB (B,NH,DH,M)

  cvt_all<<<8192 + 4096, 256, 0, stream>>>(H, Wq, Wk, Wv, Wo,
                                           Hb, Wqb, Wkb, Wvb, Wob);

  dim3 gq(8, 64, 3);
  gemm_qkv<<<gq, 256, 0, stream>>>(Hb, Wqb, Wkb, Wvb, bq, bk, bv, Qb, Kb2, Vtb);

  attn_kernel<<<dim3(M_ / 64, NH_, B_), 256, 0, stream>>>(Qb, Kb2, Vtb, pmask, Attb);

  gemm_oproj<<<dim3(16, 64), 256, 0, stream>>>(Attb, Wob, bo, pmask, out);
}

// Round 8
// 221.383 us; speedup vs baseline: 3.0563x; 3.0563x over previous
//
#include <hip/hip_runtime.h>
#include <stdint.h>

typedef short short8 __attribute__((ext_vector_type(8)));
typedef float f32x4 __attribute__((ext_vector_type(4)));

#define B_    4
#define M_    2048
#define D_    1024
#define NH_   16
#define DH_   64
#define LOG2E 1.44269504f

__device__ __forceinline__ short f2bf(float f) {
  union { float f; uint32_t u; } v; v.f = f;
  uint32_t r = (v.u + 0x7fffu + ((v.u >> 16) & 1u)) >> 16;  // RNE
  return (short)r;
}

__device__ __forceinline__ void gl_lds16(const void* g, void* l) {
  __builtin_amdgcn_global_load_lds(
      (__attribute__((address_space(1))) void*)(g),
      (__attribute__((address_space(3))) void*)(l),
      16, 0, 0);
}

__device__ __forceinline__ f32x4 mfma16(short8 a, short8 b, f32x4 c) {
  return __builtin_amdgcn_mfma_f32_16x16x32_bf16(a, b, c, 0, 0, 0);
}

// ---------------- fp32 -> bf16 cast, all 5 tensors in one launch ----------------
__global__ __launch_bounds__(256) void cvt_all(const float* __restrict__ H,
                                               const float* __restrict__ s0,
                                               const float* __restrict__ s1,
                                               const float* __restrict__ s2,
                                               const float* __restrict__ s3,
                                               short* __restrict__ dH,
                                               short* __restrict__ d0,
                                               short* __restrict__ d1,
                                               short* __restrict__ d2,
                                               short* __restrict__ d3) {
  const int bidx = blockIdx.x;
  const float* src;
  short* dst;
  int i;
  if (bidx < 8192) {
    src = H; dst = dH; i = bidx * 256 + threadIdx.x;
  } else {
    const int y = (bidx - 8192) >> 10;
    src = (y == 0) ? s0 : (y == 1) ? s1 : (y == 2) ? s2 : s3;
    dst = (y == 0) ? d0 : (y == 1) ? d1 : (y == 2) ? d2 : d3;
    i = ((bidx - 8192) & 1023) * 256 + threadIdx.x;
  }
  float4 v = ((const float4*)src)[i];
  short4 o;
  o.x = f2bf(v.x); o.y = f2bf(v.y); o.z = f2bf(v.z); o.w = f2bf(v.w);
  ((short4*)dst)[i] = o;
}

// ---------------- fused QKV projection GEMM (ping-pong K-loop) ----------------
// R6 structure + double-buffered staging: prefetch(k+1) issued BEFORE
// compute(k); ONE barrier per iter whose vmcnt drain overlaps the compute.
// Epilogue: LDS transpose -> fully-coalesced short8 stores (R7 lesson:
// scattered partial-line stores write-amplify ~30x; never again).
__global__ __launch_bounds__(256, 3) void gemm_qkv(const short* __restrict__ A,
                                                   const short* __restrict__ Wqb,
                                                   const short* __restrict__ Wkb,
                                                   const short* __restrict__ Wvb,
                                                   const float* __restrict__ bq,
                                                   const float* __restrict__ bk,
                                                   const float* __restrict__ bv,
                                                   short* __restrict__ Qo,
                                                   short* __restrict__ Ko,
                                                   short* __restrict__ Vo) {
  __shared__ char smem_raw[34816];
  short* Ab0 = (short*)smem_raw;            // 128x32 (8 KB)
  short* Ab1 = (short*)(smem_raw + 8192);
  short* Bb0 = (short*)(smem_raw + 16384);
  short* Bb1 = (short*)(smem_raw + 24576);

  const int L = blockIdx.x + 8 * (blockIdx.y + 64 * blockIdx.z);
  const int xcd = L & 7;
  const int s = L >> 3;
  const int m_local = s & 7;
  const int nz = s >> 3;
  const int nt = nz & 7, z = nz >> 3;
  const int m0 = (xcd * 8 + m_local) * 128;
  const int n0 = nt * 128;

  const short* Bt = (z == 0) ? Wqb : (z == 1) ? Wkb : Wvb;
  const float* bias = (z == 0) ? bq : (z == 1) ? bk : bv;
  const float scale = (z == 0) ? 0.125f : 1.0f;

  const int tid = threadIdx.x;
  const int w = tid >> 6, l = tid & 63;
  const int q4 = l >> 4, c = l & 15;
  const int wr = w >> 1, wc = w & 1;

  f32x4 acc[4][4] = {};
  const int arow = (l >> 2);
  const int acol = (l & 3) * 8;

  // prologue: stage tile 0 -> buf0
#pragma unroll
  for (int st = 0; st < 2; ++st) {
    const int chunk = w * 2 + st;
    gl_lds16(A + (size_t)(m0 + chunk * 16 + arow) * 1024 + acol, Ab0 + chunk * 512);
    gl_lds16(Bt + (size_t)(n0 + chunk * 16 + arow) * 1024 + acol, Bb0 + chunk * 512);
  }
  __syncthreads();

  for (int kk = 0; kk < 32; ++kk) {
    const int cur = kk & 1;
    if (kk + 1 < 32) {  // prefetch next tile into the other buffer
      const int k0n = (kk + 1) * 32;
#pragma unroll
      for (int st = 0; st < 2; ++st) {
        const int chunk = w * 2 + st;
        gl_lds16(A + (size_t)(m0 + chunk * 16 + arow) * 1024 + k0n + acol,
                 (cur ? Ab0 : Ab1) + chunk * 512);
        gl_lds16(Bt + (size_t)(n0 + chunk * 16 + arow) * 1024 + k0n + acol,
                 (cur ? Bb0 : Bb1) + chunk * 512);
      }
    }
    const short* Ab = cur ? Ab1 : Ab0;
    const short* Bb = cur ? Bb1 : Bb0;
    short8 af[4], bfr[4];
#pragma unroll
    for (int i = 0; i < 4; ++i)
      af[i] = *(const short8*)(Ab + (wr * 64 + i * 16 + c) * 32 + q4 * 8);
#pragma unroll
    for (int j = 0; j < 4; ++j)
      bfr[j] = *(const short8*)(Bb + (wc * 64 + j * 16 + c) * 32 + q4 * 8);
#pragma unroll
    for (int i = 0; i < 4; ++i)
#pragma unroll
      for (int j = 0; j < 4; ++j)
        acc[i][j] = mfma16(af[i], bfr[j], acc[i][j]);
    __syncthreads();  // drains prefetch (overlapped by the compute above)
  }

  if (z < 2) {
    short* Cb = (short*)smem_raw;
    short* out = (z == 0) ? Qo : Ko;
#pragma unroll
    for (int j = 0; j < 4; ++j) {
      const float bvv = bias[n0 + wc * 64 + j * 16 + c];
#pragma unroll
      for (int i = 0; i < 4; ++i)
#pragma unroll
        for (int r = 0; r < 4; ++r)
          Cb[(wr * 64 + i * 16 + q4 * 4 + r) * 136 + wc * 64 + j * 16 + c] =
              f2bf((acc[i][j][r] + bvv) * scale);
    }
    __syncthreads();
#pragma unroll
    for (int p = 0; p < 8; ++p) {
      const int g = p * 256 + tid;
      const int row = g >> 4, seg = g & 15;
      *(short8*)(out + (size_t)(m0 + row) * 1024 + n0 + seg * 8) =
          *(const short8*)(Cb + row * 136 + seg * 8);
    }
  } else {
    short* Cb = (short*)smem_raw;
#pragma unroll
    for (int j = 0; j < 4; ++j) {
      const float bvv = bias[n0 + wc * 64 + j * 16 + c];
#pragma unroll
      for (int i = 0; i < 4; ++i) {
        short4 pk;
        pk.x = f2bf(acc[i][j][0] + bvv);
        pk.y = f2bf(acc[i][j][1] + bvv);
        pk.z = f2bf(acc[i][j][2] + bvv);
        pk.w = f2bf(acc[i][j][3] + bvv);
        *(short4*)(Cb + (wc * 64 + j * 16 + c) * 136 + wr * 64 + i * 16 + q4 * 4) = pk;
      }
    }
    __syncthreads();
    const int bb = m0 >> 11;
    const int tokb = m0 & 2047;
#pragma unroll
    for (int p = 0; p < 8; ++p) {
      const int g = p * 256 + tid;
      const int col = g >> 4, rseg = g & 15;
      const int colg = n0 + col;
      const int hh = colg >> 6, dd = colg & 63;
      *(short8*)(Vo + ((size_t)(bb * NH_ + hh) * DH_ + dd) * M_ + tokb + rseg * 8) =
          *(const short8*)(Cb + col * 136 + rseg * 8);
    }
  }
}

// ---------------- output projection GEMM (ping-pong K-loop, LDS fp32 epi) ----------------
__global__ __launch_bounds__(256) void gemm_oproj(const short* __restrict__ A,
                                                  const short* __restrict__ Bt,
                                                  const float* __restrict__ bias,
                                                  const int* __restrict__ pmask,
                                                  float* __restrict__ outp) {
  __shared__ char smem[24576];
  short* Ab0 = (short*)smem;             // 128x32 (8 KB)
  short* Ab1 = (short*)(smem + 8192);
  short* Bb0 = (short*)(smem + 16384);   // 64x32 (4 KB)
  short* Bb1 = (short*)(smem + 20480);

  const int L = blockIdx.x + 16 * blockIdx.y;  // 1024 blocks
  const int xcd = L & 7;
  const int s = L >> 3;
  const int m_local = s & 7;
  const int nt = s >> 3;
  const int m0 = (xcd * 8 + m_local) * 128;
  const int n0 = nt * 64;

  const int tid = threadIdx.x;
  const int w = tid >> 6, l = tid & 63;
  const int q4 = l >> 4, c = l & 15;
  const int wr = w >> 1, wc = w & 1;

  f32x4 acc[4][2] = {};
  const int arow = (l >> 2);
  const int acol = (l & 3) * 8;

  // prologue: tile 0 -> buf0
#pragma unroll
  for (int st = 0; st < 2; ++st) {
    const int chunk = w * 2 + st;
    gl_lds16(A + (size_t)(m0 + chunk * 16 + arow) * 1024 + acol, Ab0 + chunk * 512);
  }
  gl_lds16(Bt + (size_t)(n0 + w * 16 + arow) * 1024 + acol, Bb0 + w * 512);
  __syncthreads();

  for (int kk = 0; kk < 32; ++kk) {
    const int cur = kk & 1;
    if (kk + 1 < 32) {
      const int k0n = (kk + 1) * 32;
#pragma unroll
      for (int st = 0; st < 2; ++st) {
        const int chunk = w * 2 + st;
        gl_lds16(A + (size_t)(m0 + chunk * 16 + arow) * 1024 + k0n + acol,
                 (cur ? Ab0 : Ab1) + chunk * 512);
      }
      gl_lds16(Bt + (size_t)(n0 + w * 16 + arow) * 1024 + k0n + acol,
               (cur ? Bb0 : Bb1) + w * 512);
    }
    const short* Ab = cur ? Ab1 : Ab0;
    const short* Bb = cur ? Bb1 : Bb0;
    short8 af[4], bfr[2];
#pragma unroll
    for (int i = 0; i < 4; ++i)
      af[i] = *(const short8*)(Ab + (wr * 64 + i * 16 + c) * 32 + q4 * 8);
#pragma unroll
    for (int j = 0; j < 2; ++j)
      bfr[j] = *(const short8*)(Bb + (wc * 32 + j * 16 + c) * 32 + q4 * 8);
#pragma unroll
    for (int i = 0; i < 4; ++i)
#pragma unroll
      for (int j = 0; j < 2; ++j)
        acc[i][j] = mfma16(af[i], bfr[j], acc[i][j]);
    __syncthreads();
  }

  // fp32 epilogue: two 64-row halves through LDS [64][68], float4 stores
  float* Cf = (float*)smem;
#pragma unroll
  for (int half = 0; half < 2; ++half) {
    __syncthreads();
    if (wr == half) {
#pragma unroll
      for (int j = 0; j < 2; ++j) {
        const float bvv = bias[n0 + wc * 32 + j * 16 + c];
#pragma unroll
        for (int i = 0; i < 4; ++i)
#pragma unroll
          for (int r = 0; r < 4; ++r)
            Cf[(i * 16 + q4 * 4 + r) * 68 + wc * 32 + j * 16 + c] =
                acc[i][j][r] + bvv;
      }
    }
    __syncthreads();
#pragma unroll
    for (int p = 0; p < 4; ++p) {
      const int g = p * 256 + tid;
      const int row = g >> 4, seg = g & 15;
      const int rowg = m0 + half * 64 + row;
      const float mmv = (pmask[rowg] > 0) ? 1.0f : 0.0f;
      float4 v = *(const float4*)(Cf + row * 68 + seg * 4);
      v.x *= mmv; v.y *= mmv; v.z *= mmv; v.w *= mmv;
      *(float4*)(outp + (size_t)rowg * 1024 + n0 + seg * 4) = v;
    }
  }
}

// ---------------- windowed attention (unchanged from R6) ----------------
__global__ __launch_bounds__(256) void attn_kernel(const short* __restrict__ Qb,
                                                   const short* __restrict__ Kb,
                                                   const short* __restrict__ Vtb,
                                                   const int* __restrict__ pmask,
                                                   short* __restrict__ Attb) {
  __shared__ char smem[20480];
  short* Ks0 = (short*)smem;             // 32x64 (4 KB)
  short* Ks1 = (short*)(smem + 4096);
  short* Vs0 = (short*)(smem + 8192);    // 64x32 (4 KB)
  short* Vs1 = (short*)(smem + 12288);
  short* Ps  = (short*)(smem + 16384);   // 4 waves x 16x32 (4 KB)

  const int tid = threadIdx.x;
  const int w = tid >> 6, l = tid & 63;
  const int q4 = l >> 4, c = l & 15;
  const int qt = blockIdx.x, h = blockIdx.y, b = blockIdx.z;
  const short* Qrow = Qb + (size_t)(b * M_) * D_ + h * DH_;
  const short* Kbase = Kb + (size_t)(b * M_) * D_ + h * DH_;
  const short* Vbase = Vtb + (size_t)(b * NH_ + h) * DH_ * M_;
  const int qrow0 = qt * 64 + w * 16;

  short8 aq0 = *(const short8*)(Qrow + (size_t)(qrow0 + c) * D_ + q4 * 8);
  short8 aq1 = *(const short8*)(Qrow + (size_t)(qrow0 + c) * D_ + 32 + q4 * 8);

  const int jt0 = max(0, 2 * qt - 2);
  const int jt1 = min(M_ / 32 - 1, 2 * qt + 3);

  const int kh = tid >> 7, krow = (tid >> 2) & 31, ch = tid & 3;
  const int vrow = tid >> 2;

  {
    const int j0 = jt0 * 32;
    gl_lds16(Kbase + (size_t)(j0 + krow) * D_ + kh * 32 + ch * 8, (char*)Ks0 + tid * 16);
    gl_lds16(Vbase + (size_t)vrow * M_ + j0 + ch * 8, (char*)Vs0 + tid * 16);
  }
  __syncthreads();

  f32x4 o[4] = {};
  float lrun[4] = {0.f, 0.f, 0.f, 0.f};
  short* Pw = Ps + w * 512;

  for (int jt = jt0; jt <= jt1; ++jt) {
    const int buf = (jt - jt0) & 1;
    const int j0 = jt * 32;
    if (jt < jt1) {
      const int j0n = j0 + 32;
      gl_lds16(Kbase + (size_t)(j0n + krow) * D_ + kh * 32 + ch * 8,
               (char*)(buf ? Ks0 : Ks1) + tid * 16);
      gl_lds16(Vbase + (size_t)vrow * M_ + j0n + ch * 8,
               (char*)(buf ? Vs0 : Vs1) + tid * 16);
    }
    const short* Kt = buf ? Ks1 : Ks0;
    const short* Vt = buf ? Vs1 : Vs0;
    short8 b00 = *(const short8*)(Kt + c * 32 + q4 * 8);
    short8 b10 = *(const short8*)(Kt + 1024 + c * 32 + q4 * 8);
    short8 b01 = *(const short8*)(Kt + (16 + c) * 32 + q4 * 8);
    short8 b11 = *(const short8*)(Kt + 1024 + (16 + c) * 32 + q4 * 8);
    f32x4 s0 = {}, s1 = {};
    s0 = mfma16(aq0, b00, s0);
    s0 = mfma16(aq1, b10, s0);
    s1 = mfma16(aq0, b01, s1);
    s1 = mfma16(aq1, b11, s1);

    const float w0m = (pmask[b * M_ + j0 + c] > 0) ? 1.f : 0.f;
    const float w1m = (pmask[b * M_ + j0 + 16 + c] > 0) ? 1.f : 0.f;

#pragma unroll
    for (int r = 0; r < 4; ++r) {
      const int qr = qrow0 + q4 * 4 + r;
      const float d0 = fminf(fabsf((float)(qr - (j0 + c))), 28.0f);
      const float d1 = fminf(fabsf((float)(qr - (j0 + 16 + c))), 28.0f);
      const float p0 = exp2f((s0[r] - d0) * LOG2E) * w0m;
      const float p1 = exp2f((s1[r] - d1) * LOG2E) * w1m;
      Pw[(q4 * 4 + r) * 32 + c] = f2bf(p0);
      Pw[(q4 * 4 + r) * 32 + 16 + c] = f2bf(p1);
      lrun[r] += p0 + p1;
    }
    short8 pa = *(const short8*)(Pw + c * 32 + q4 * 8);
#pragma unroll
    for (int f = 0; f < 4; ++f) {
      short8 bv = *(const short8*)(Vt + (f * 16 + c) * 32 + q4 * 8);
      o[f] = mfma16(pa, bv, o[f]);
    }
    __syncthreads();
  }

#pragma unroll
  for (int r = 0; r < 4; ++r) {
#pragma unroll
    for (int off = 1; off < 16; off <<= 1)
      lrun[r] += __shfl_xor(lrun[r], off);
  }

  short* Cb = (short*)smem;
#pragma unroll
  for (int r = 0; r < 4; ++r) {
    const float inv = 1.0f / lrun[r];
#pragma unroll
    for (int f = 0; f < 4; ++f)
      Cb[(w * 16 + q4 * 4 + r) * 72 + f * 16 + c] = f2bf(o[f][r] * inv);
  }
  __syncthreads();
#pragma unroll
  for (int p = 0; p < 2; ++p) {
    const int u = p * 256 + tid;
    const int row = u >> 3, seg = u & 7;
    *(short8*)(Attb + (size_t)(b * M_ + qt * 64 + row) * D_ + h * DH_ + seg * 8) =
        *(const short8*)(Cb + row * 72 + seg * 8);
  }
}

extern "C" void kernel_launch(void* const* d_in, const int* in_sizes, int n_in,
                              void* d_out, int out_size, void* d_ws, size_t ws_size,
                              hipStream_t stream) {
  const float* H     = (const float*)d_in[0];
  const int*   pmask = (const int*)d_in[1];
  const float* Wq    = (const float*)d_in[2];
  const float* bq    = (const float*)d_in[3];
  const float* Wk    = (const float*)d_in[4];
  const float* bk    = (const float*)d_in[5];
  const float* Wv    = (const float*)d_in[6];
  const float* bv    = (const float*)d_in[7];
  const float* Wo    = (const float*)d_in[8];
  const float* bo    = (const float*)d_in[9];
  float* out = (float*)d_out;
  char* ws = (char*)d_ws;

  short* Hb   = (short*)(ws);                  // 16 MB  (B*M x D bf16)
  short* Attb = (short*)(ws);                  // alias of Hb (dead after qkv)
  short* Wqb  = (short*)(ws + (16u << 20));
  short* Wkb  = (short*)(ws + (18u << 20));
  short* Wvb  = (short*)(ws + (20u << 20));
  short* Wob  = (short*)(ws + (22u << 20));
  short* Qb   = (short*)(ws + (24u << 20));    // 16 MB (B*M,1024), pre-scaled 1/8
  short* Kb2  = (short*)(ws + (40u << 20));    // 16 MB (B*M,1024)
  short* Vtb  = (short*)(ws + (56u << 20));    // 16 MB (B,NH,DH,M)

  cvt_all<<<8192 + 4096, 256, 0, stream>>>(H, Wq, Wk, Wv, Wo,
                                           Hb, Wqb, Wkb, Wvb, Wob);

  dim3 gq(8, 64, 3);
  gemm_qkv<<<gq, 256, 0, stream>>>(Hb, Wqb, Wkb, Wvb, bq, bk, bv, Qb, Kb2, Vtb);

  attn_kernel<<<dim3(M_ / 64, NH_, B_), 256, 0, stream>>>(Qb, Kb2, Vtb, pmask, Attb);

  gemm_oproj<<<dim3(16, 64), 256, 0, stream>>>(Attb, Wob, bo, pmask, out);
}